// Round 16
// baseline (1065.890 us; speedup 1.0000x reference)
//
#include <hip/hip_runtime.h>
#include <math.h>

#define G 200
#define NF 128
#define EF 64

typedef __attribute__((ext_vector_type(8))) short bf16x8;
typedef __attribute__((ext_vector_type(4))) float f32x4;

__device__ __forceinline__ float leakyf(float x) { return x > 0.f ? x : 0.01f * x; }
__device__ __forceinline__ float eluf(float x)   { return x > 0.f ? x : (expf(x) - 1.f); }
__device__ __forceinline__ float sigm(float x)   { return 1.f / (1.f + expf(-x)); }

__device__ __forceinline__ unsigned short f2bf(float x) {
    union { float f; unsigned int u; } v; v.f = x;
    unsigned int r = v.u + 0x7FFF + ((v.u >> 16) & 1);   // RNE
    return (unsigned short)(r >> 16);
}
__device__ __forceinline__ float bf2f(unsigned short u) {
    union { unsigned int i; float f; } v; v.i = ((unsigned int)u) << 16;
    return v.f;
}
__device__ __forceinline__ unsigned int pk2(float a, float b) {
    return (unsigned int)f2bf(a) | ((unsigned int)f2bf(b) << 16);
}

// ---------- generic weight transpose+bf16 prep: Wt[208][kpad] = W[k][n] ----------
__global__ __launch_bounds__(256) void tprep_k(
    const float* __restrict__ W, unsigned short* __restrict__ Wt,
    int Kreal, int kpad, int Nstride, int Nreal)
{
    int total = 208 * kpad;
    for (int i = blockIdx.x * 256 + threadIdx.x; i < total; i += gridDim.x * 256) {
        int n = i / kpad, k = i % kpad;
        Wt[i] = (n < Nreal && k < Kreal) ? f2bf(W[(size_t)k * Nstride + n]) : 0;
    }
}

// ---------- bf16 pack (elementwise, 8/thread): Y = bf16(X) ----------
__global__ __launch_bounds__(256) void bfpack_k(
    const float* __restrict__ X, unsigned short* __restrict__ Y, long n8)
{
    for (long i = (long)blockIdx.x * 256 + threadIdx.x; i < n8;
         i += (long)gridDim.x * 256) {
        const float4* xp = (const float4*)(X + i * 8);
        float4 a = xp[0], b = xp[1];
        uint4 u; u.x = pk2(a.x, a.y); u.y = pk2(a.z, a.w);
        u.z = pk2(b.x, b.y); u.w = pk2(b.z, b.w);
        *(uint4*)&Y[i * 8] = u;
    }
}

// ---------- GRU weight prep for the tiled GEMM ----------
__global__ __launch_bounds__(256) void wgru3_k(
    const float* __restrict__ Wx, const float* __restrict__ Wh,
    unsigned short* __restrict__ Btrz, unsigned short* __restrict__ Btn)
{
    const int total = 512 * 416;
    for (int i = blockIdx.x * 256 + threadIdx.x; i < total; i += gridDim.x * 256) {
        int n = i / 416, k = i % 416;
        float v = 0.f;
        if (n < 416) {
            int gg = (n >= 208) ? 1 : 0;
            int c = n - gg * 208;
            if (c < 200) {
                if (k < 200)                  v = Wx[(size_t)k * 600 + gg * 200 + c];
                else if (k >= 208 && k < 408) v = Wh[(size_t)(k - 208) * 600 + gg * 200 + c];
            }
        }
        Btrz[i] = f2bf(v);

        float u = 0.f;
        int s = n >> 4, cc = n & 15;
        if (s < 26) {
            int c = (s >> 1) * 16 + cc;
            if (c < 200) {
                if (!(s & 1)) { if (k < 200) u = Wx[(size_t)k * 600 + 400 + c]; }
                else { if (k >= 208 && k < 408) u = Wh[(size_t)(k - 208) * 600 + 400 + c]; }
            }
        }
        Btn[i] = f2bf(u);
    }
}

// ---------- tiled 128x128 GEMM, K=416, double-buffered LDS, bf16 MFMA ----------
// EPI 0: RZ[row*416+col] = f16(sigm(acc + bias))
// EPI 1: GRU combine with h read from f32 Hf
template <int EPI>
__global__ __launch_bounds__(256) void tgemm_k(
    const unsigned short* __restrict__ Apk,
    const unsigned short* __restrict__ Bt,
    const float* __restrict__ bx, const float* __restrict__ bh,
    _Float16* __restrict__ RZ,
    const float* __restrict__ Hf,
    float* __restrict__ OUT, int M)
{
    __shared__ __align__(16) unsigned short As[2][128 * 32];
    __shared__ __align__(16) unsigned short Bs[2][128 * 32];

    const int tid = threadIdx.x;
    const int w = tid >> 6, lane = tid & 63, l15 = lane & 15, lq = lane >> 4;
    const int wr = w >> 1, wc = w & 1;
    const int bm = blockIdx.x * 128, bn = blockIdx.y * 128;
    const int r0 = tid >> 2, sl = tid & 3;

    f32x4 acc[4][4];
#pragma unroll
    for (int a = 0; a < 4; ++a)
#pragma unroll
        for (int b = 0; b < 4; ++b) acc[a][b] = (f32x4){0.f, 0.f, 0.f, 0.f};

    {
        uint4 pa0 = *(const uint4*)&Apk[(size_t)(bm + r0) * 416 + sl * 8];
        uint4 pa1 = *(const uint4*)&Apk[(size_t)(bm + 64 + r0) * 416 + sl * 8];
        uint4 pb0 = *(const uint4*)&Bt[(size_t)(bn + r0) * 416 + sl * 8];
        uint4 pb1 = *(const uint4*)&Bt[(size_t)(bn + 64 + r0) * 416 + sl * 8];
        int w0 = sl ^ ((r0 >> 1) & 3), w1 = sl ^ (((r0 + 64) >> 1) & 3);
        *(uint4*)&As[0][r0 * 32 + w0 * 8] = pa0;
        *(uint4*)&As[0][(r0 + 64) * 32 + w1 * 8] = pa1;
        *(uint4*)&Bs[0][r0 * 32 + w0 * 8] = pb0;
        *(uint4*)&Bs[0][(r0 + 64) * 32 + w1 * 8] = pb1;
    }
    __syncthreads();

    int cur = 0;
    for (int c = 0; c < 13; ++c) {
        uint4 pa0, pa1, pb0, pb1;
        if (c < 12) {
            int kc = (c + 1) * 32;
            pa0 = *(const uint4*)&Apk[(size_t)(bm + r0) * 416 + kc + sl * 8];
            pa1 = *(const uint4*)&Apk[(size_t)(bm + 64 + r0) * 416 + kc + sl * 8];
            pb0 = *(const uint4*)&Bt[(size_t)(bn + r0) * 416 + kc + sl * 8];
            pb1 = *(const uint4*)&Bt[(size_t)(bn + 64 + r0) * 416 + kc + sl * 8];
        }
        bf16x8 af[4], bfr[4];
#pragma unroll
        for (int s = 0; s < 4; ++s) {
            int ra = wr * 64 + s * 16 + l15;
            af[s] = *(const bf16x8*)&As[cur][ra * 32 + (lq ^ ((ra >> 1) & 3)) * 8];
            int rb = wc * 64 + s * 16 + l15;
            bfr[s] = *(const bf16x8*)&Bs[cur][rb * 32 + (lq ^ ((rb >> 1) & 3)) * 8];
        }
#pragma unroll
        for (int sr = 0; sr < 4; ++sr)
#pragma unroll
            for (int sc = 0; sc < 4; ++sc)
                acc[sr][sc] = __builtin_amdgcn_mfma_f32_16x16x32_bf16(
                    af[sr], bfr[sc], acc[sr][sc], 0, 0, 0);

        if (c < 12) {
            int nb = cur ^ 1;
            int w0 = sl ^ ((r0 >> 1) & 3), w1 = sl ^ (((r0 + 64) >> 1) & 3);
            *(uint4*)&As[nb][r0 * 32 + w0 * 8] = pa0;
            *(uint4*)&As[nb][(r0 + 64) * 32 + w1 * 8] = pa1;
            *(uint4*)&Bs[nb][r0 * 32 + w0 * 8] = pb0;
            *(uint4*)&Bs[nb][(r0 + 64) * 32 + w1 * 8] = pb1;
        }
        __syncthreads();
        cur ^= 1;
    }

    if (EPI == 0) {
#pragma unroll
        for (int sr = 0; sr < 4; ++sr)
#pragma unroll
            for (int sc = 0; sc < 4; ++sc) {
                int col = bn + wc * 64 + sc * 16 + l15;
                if (col >= 416) continue;
                float bsum = (col < 208) ? (bx[col] + bh[col])
                                         : (bx[col - 8] + bh[col - 8]);
#pragma unroll
                for (int i = 0; i < 4; ++i) {
                    int row = bm + wr * 64 + sr * 16 + lq * 4 + i;
                    if (row < M)
                        RZ[(size_t)row * 416 + col] =
                            (_Float16)sigm(acc[sr][sc][i] + bsum);
                }
            }
    } else {
#pragma unroll
        for (int p = 0; p < 2; ++p) {
            int sglob = (bn >> 4) + wc * 4 + 2 * p;
            int cc = (sglob >> 1) * 16 + l15;
            if (cc >= 200) continue;
            float bxn = bx[400 + cc], bhn = bh[400 + cc];
#pragma unroll
            for (int sr = 0; sr < 4; ++sr)
#pragma unroll
                for (int i = 0; i < 4; ++i) {
                    int row = bm + wr * 64 + sr * 16 + lq * 4 + i;
                    if (row >= M) continue;
                    float rr = (float)RZ[(size_t)row * 416 + cc];
                    float zz = (float)RZ[(size_t)row * 416 + 208 + cc];
                    float hh = Hf[(size_t)row * 200 + cc];
                    float nn = tanhf(acc[sr][2 * p][i] + bxn +
                                     rr * (acc[sr][2 * p + 1][i] + bhn));
                    float o = (1.f - zz) * nn + zz * hh;
                    OUT[(size_t)row * 200 + cc] = fmaxf(o, 0.f);
                }
        }
    }
}

// ---------- CSR build ----------
__global__ __launch_bounds__(256) void hist_k(
    const int* __restrict__ dst, int* __restrict__ cnt, int E)
{
    int i = blockIdx.x * 256 + threadIdx.x;
    if (i < E) atomicAdd(&cnt[dst[i]], 1);
}

__global__ __launch_bounds__(256) void scan_k(
    const int* __restrict__ cnt, int* __restrict__ offs,
    int* __restrict__ cursor, int Nn)
{
    __shared__ int wsum[4];
    const int tid = threadIdx.x;
    const int lane = tid & 63, wv = tid >> 6;
    int carry = 0;
    const int CH = 8;
    for (int base = 0; base < Nn; base += 256 * CH) {
        int v[CH]; int tsum = 0;
        int i0 = base + tid * CH;
#pragma unroll
        for (int j = 0; j < CH; ++j) {
            v[j] = (i0 + j < Nn) ? cnt[i0 + j] : 0;
            tsum += v[j];
        }
        int x = tsum;
        for (int off = 1; off < 64; off <<= 1) {
            int t = __shfl_up(x, off);
            if (lane >= off) x += t;
        }
        if (lane == 63) wsum[wv] = x;
        __syncthreads();
        int wbase = 0;
#pragma unroll
        for (int wq = 0; wq < 4; ++wq) wbase += (wq < wv) ? wsum[wq] : 0;
        int gtot = wsum[0] + wsum[1] + wsum[2] + wsum[3];
        int run = carry + wbase + (x - tsum);
#pragma unroll
        for (int j = 0; j < CH; ++j) {
            int idx = i0 + j;
            if (idx < Nn) { offs[idx] = run; cursor[idx] = run; }
            run += v[j];
        }
        carry += gtot;
        __syncthreads();
    }
    if (tid == 0) offs[Nn] = carry;
}

__global__ __launch_bounds__(256) void scatter_k(
    const int* __restrict__ src, const int* __restrict__ dst,
    int* __restrict__ cursor, int* __restrict__ eidC,
    int* __restrict__ srcC, int* __restrict__ dstC, int E)
{
    int i = blockIdx.x * 256 + threadIdx.x;
    if (i < E) {
        int d = dst[i];
        int pos = atomicAdd(&cursor[d], 1);
        eidC[pos] = i; srcC[pos] = src[i]; dstC[pos] = d;
    }
}

// ---------- dense MFMA GEMM (64-row) with fused A-pack epilogues ----------
// amode 0: OUT f32 = (leaky?)v
// amode 1: APK X-half (stride 416) = bf16(elu(v))
// amode 2: OUT f32 = leaky(v)  AND  APK H-half (stride 416) = bf16(leaky(v))
// amode 3: APK (stride 200) = bf16(v)            (bf16 hvp for layer2b)
__global__ __launch_bounds__(256) void mgemm_k(
    const float* __restrict__ X, const unsigned short* __restrict__ Wt,
    const float* __restrict__ bias, float* __restrict__ OUT,
    unsigned short* __restrict__ APK, int amode,
    int M, int Kreal, int kch, int astr, int leaky,
    const float* __restrict__ xdiv)
{
    __shared__ __align__(16) unsigned short A[64 * 232];
    const int tid = threadIdx.x;
    const int w = tid >> 6, lane = tid & 63, l15 = lane & 15, lq = lane >> 4;
    const int bm = blockIdx.x * 64;
    const int kpad = kch * 32;
    const int nch8 = Kreal >> 3;

    for (int i = tid; i < 64 * nch8; i += 256) {
        int r = i / nch8, ch = i % nch8;
        int grow = bm + r;
        uint4 u = make_uint4(0, 0, 0, 0);
        if (grow < M) {
            const float4* xp = (const float4*)(X + (size_t)grow * Kreal + ch * 8);
            float inv = 1.f;
            if (xdiv) { float dv = xdiv[grow]; inv = (dv > 0.f) ? 1.f / dv : 0.f; }
            float4 a = xp[0], b = xp[1];
            u.x = pk2(a.x * inv, a.y * inv); u.y = pk2(a.z * inv, a.w * inv);
            u.z = pk2(b.x * inv, b.y * inv); u.w = pk2(b.z * inv, b.w * inv);
        }
        *(uint4*)&A[r * astr + ch * 8] = u;
    }
    if (tid < 64) {
        for (int p = Kreal; p < kpad; p += 8)
            *(uint4*)&A[tid * astr + p] = make_uint4(0, 0, 0, 0);
    }
    __syncthreads();

    const int arow = (w * 16 + l15) * astr;
    f32x4 acc[13];
#pragma unroll
    for (int t = 0; t < 13; ++t) acc[t] = (f32x4){0.f, 0.f, 0.f, 0.f};

    for (int c = 0; c < kch; ++c) {
        bf16x8 a = *(const bf16x8*)&A[arow + c * 32 + lq * 8];
#pragma unroll
        for (int t = 0; t < 13; ++t) {
            bf16x8 b = *(const bf16x8*)&Wt[(size_t)(t * 16 + l15) * kpad + c * 32 + lq * 8];
            acc[t] = __builtin_amdgcn_mfma_f32_16x16x32_bf16(a, b, acc[t], 0, 0, 0);
        }
    }

    float rg[4];
#pragma unroll
    for (int i = 0; i < 4; ++i) {
        int grow = bm + w * 16 + lq * 4 + i;
        rg[i] = 1.f;
        if (xdiv && grow < M) rg[i] = (xdiv[grow] > 0.f) ? 1.f : 0.f;
    }

#pragma unroll
    for (int t = 0; t < 13; ++t) {
        int col = t * 16 + l15;
        if (col >= 200) continue;
        float bs = bias[col];
#pragma unroll
        for (int i = 0; i < 4; ++i) {
            int grow = bm + w * 16 + lq * 4 + i;
            if (grow >= M) continue;
            float v = acc[t][i] + bs * rg[i];
            if (amode == 0) {
                OUT[(size_t)grow * 200 + col] = leaky ? leakyf(v) : v;
            } else if (amode == 1) {
                APK[(size_t)grow * 416 + col] = f2bf(eluf(v));
            } else if (amode == 2) {
                float lv = leakyf(v);
                OUT[(size_t)grow * 200 + col] = lv;
                APK[(size_t)grow * 416 + 208 + col] = f2bf(lv);
            } else {
                APK[(size_t)grow * 200 + col] = f2bf(v);
            }
        }
    }
}

// ---------------- hd[n] = x[n,:] . W[0:200] ----------------
__global__ __launch_bounds__(256) void hd_k(
    const float* __restrict__ x, const float* __restrict__ W,
    float* __restrict__ hd, int Nn)
{
    int wid = blockIdx.x * 4 + (threadIdx.x >> 6);
    int lane = threadIdx.x & 63;
    if (wid >= Nn) return;
    float s = 0.f;
    for (int j = lane; j < G; j += 64) s += x[(size_t)wid * G + j] * W[j];
    for (int off = 32; off; off >>= 1) s += __shfl_down(s, off);
    if (lane == 0) hd[wid] = s;
}

// -------- hd2/hs pair + pack h into apack H-half (GRU2's H) --------
__global__ __launch_bounds__(256) void hdpair_k(
    const float* __restrict__ x, const float* __restrict__ W,
    float* __restrict__ hd2, float* __restrict__ hs,
    unsigned short* __restrict__ APK, int Nn)
{
    int wid = blockIdx.x * 4 + (threadIdx.x >> 6);
    int lane = threadIdx.x & 63;
    if (wid >= Nn) return;
    float s1 = 0.f, s2 = 0.f;
    unsigned short* ap = APK + (size_t)wid * 416 + 208;
    for (int j = lane; j < G; j += 64) {
        float v = x[(size_t)wid * G + j];
        s1 = fmaf(v, W[j], s1);
        s2 = fmaf(v, W[200 + j], s2);
        ap[j] = f2bf(v);
    }
    for (int off = 32; off; off >>= 1) {
        s1 += __shfl_down(s1, off);
        s2 += __shfl_down(s2, off);
    }
    if (lane == 0) { hd2[wid] = s1; hs[wid] = s2; }
}

// ============ fused edge kernel (CSR order, MFMA bf16, pipelined W staging) ============
__global__ __launch_bounds__(256) void edgefuse2_k(
    const unsigned short* __restrict__ nodebf, const float* __restrict__ edgef,
    const int* __restrict__ srcC, const int* __restrict__ dstC,
    const int* __restrict__ eidC,
    const unsigned short* __restrict__ W1t, const float* __restrict__ b1,
    const float* __restrict__ e2W, const float* __restrict__ e2b,
    const float* __restrict__ hd,
    float* __restrict__ sden, float* __restrict__ hacc, int E)
{
    __shared__ __align__(16) unsigned short U[64 * 216];
    __shared__ __align__(16) unsigned short Wt[208 * 40];
    __shared__ float rowlg[64];
    __shared__ float pexp_s[64];
    __shared__ int   dst_s[64];

    const int tid  = threadIdx.x;
    const int w    = tid >> 6;
    const int lane = tid & 63;
    const int l15  = lane & 15;
    const int lq   = lane >> 4;
    const int eb   = blockIdx.x * 64;

    {
        const int r4 = tid >> 2, q = tid & 3;
        const int pos = eb + r4;
        if (pos < E) {
            const int se = srcC[pos];
            const int ei = eidC[pos];
            const uint4* np = (const uint4*)(nodebf + (size_t)se * NF);
            const float4* ep = (const float4*)(edgef + (size_t)ei * EF);
            uint4* rowp = (uint4*)(U + r4 * 216);
#pragma unroll
            for (int i = 0; i < 4; ++i)
                rowp[q * 4 + i] = np[q * 4 + i];
            uint4* edp = (uint4*)(U + r4 * 216 + 128);
#pragma unroll
            for (int i = 0; i < 2; ++i) {
                float4 a = ep[q * 4 + 2 * i];
                float4 b = ep[q * 4 + 2 * i + 1];
                uint4 u; u.x = pk2(a.x, a.y); u.y = pk2(a.z, a.w);
                u.z = pk2(b.x, b.y); u.w = pk2(b.z, b.w);
                edp[q * 2 + i] = u;
            }
        } else {
            uint4 z = make_uint4(0, 0, 0, 0);
            uint4* rowp = (uint4*)(U + r4 * 216);
#pragma unroll
            for (int i = 0; i < 4; ++i) rowp[q * 4 + i] = z;
            uint4* edp = (uint4*)(U + r4 * 216 + 128);
            edp[q * 2] = z; edp[q * 2 + 1] = z;
        }
        if (tid < 64) dst_s[tid] = (eb + tid < E) ? dstC[eb + tid] : -1;
    }

    // ---- software-pipelined W staging: preload chunk 0 into registers ----
    uint4 wreg[4];
#pragma unroll
    for (int j = 0; j < 4; ++j) {
        int q = tid + 256 * j;
        if (q < 832)
            wreg[j] = *(const uint4*)(W1t + (size_t)(q >> 2) * 192 + (q & 3) * 8);
    }
    __syncthreads();

    f32x4 acc[13];
#pragma unroll
    for (int t = 0; t < 13; ++t) acc[t] = (f32x4){0.f, 0.f, 0.f, 0.f};

    for (int c = 0; c < 6; ++c) {
        // write current chunk (in registers) to LDS
#pragma unroll
        for (int j = 0; j < 4; ++j) {
            int q = tid + 256 * j;
            if (q < 832)
                *(uint4*)(Wt + (q >> 2) * 40 + (q & 3) * 8) = wreg[j];
        }
        __syncthreads();
        // issue next chunk's global loads (latency hidden under MFMA)
        if (c < 5) {
#pragma unroll
            for (int j = 0; j < 4; ++j) {
                int q = tid + 256 * j;
                if (q < 832)
                    wreg[j] = *(const uint4*)(W1t + (size_t)(q >> 2) * 192 +
                                              (c + 1) * 32 + (q & 3) * 8);
            }
        }
        bf16x8 a = *(const bf16x8*)(U + (w * 16 + l15) * 216 + c * 32 + lq * 8);
#pragma unroll
        for (int t = 0; t < 13; ++t) {
            bf16x8 b = *(const bf16x8*)(Wt + (t * 16 + l15) * 40 + lq * 8);
            acc[t] = __builtin_amdgcn_mfma_f32_16x16x32_bf16(a, b, acc[t], 0, 0, 0);
        }
        __syncthreads();
    }

    float p[4] = {0.f, 0.f, 0.f, 0.f};
#pragma unroll
    for (int t = 0; t < 13; ++t) {
        const int col = t * 16 + l15;
#pragma unroll
        for (int r = 0; r < 4; ++r) {
            const int row = w * 16 + lq * 4 + r;
            float v = 0.f;
            if (col < 200) {
                v = leakyf(acc[t][r] + b1[col]);
                p[r] = fmaf(v, e2W[200 + col], p[r]);
            }
            U[row * 216 + col] = f2bf(v);
        }
    }
#pragma unroll
    for (int r = 0; r < 4; ++r) {
        p[r] += __shfl_xor(p[r], 1);
        p[r] += __shfl_xor(p[r], 2);
        p[r] += __shfl_xor(p[r], 4);
        p[r] += __shfl_xor(p[r], 8);
    }
    if (l15 == 0) {
#pragma unroll
        for (int r = 0; r < 4; ++r) rowlg[w * 16 + lq * 4 + r] = p[r];
    }
    __syncthreads();

    if (tid < 64) {
        float pe = 0.f;
        if (eb + tid < E) {
            float l = leakyf(rowlg[tid] + hd[dst_s[tid]] + e2b[0]);
            pe = expf(l);
            atomicAdd(&sden[dst_s[tid]], pe);
        }
        pexp_s[tid] = pe;
    }
    __syncthreads();

    if (tid < 200) {
        const int c = tid;
        float s = 0.f;
        int cur = dst_s[0];
        for (int r = 0; r < 64; ++r) {
            int d = dst_s[r];
            if (d < 0) break;
            if (d != cur) {
                atomicAdd(&hacc[(size_t)cur * 200 + c], s);
                s = 0.f; cur = d;
            }
            s = fmaf(pexp_s[r], bf2f(U[r * 216 + c]), s);
        }
        atomicAdd(&hacc[(size_t)cur * 200 + c], s);
    }
}

// ============ layer-2: separable logits + softmax; bf16 hvp gather, 2-way ILP ============
__global__ __launch_bounds__(256) void layer2b_k(
    const unsigned short* __restrict__ hvpbf,
    const float* __restrict__ hd2, const float* __restrict__ hs,
    const float* __restrict__ b,
    const int* __restrict__ offs, const int* __restrict__ srcC,
    unsigned short* __restrict__ APK, int Nn)
{
    const int wv = threadIdx.x >> 6;
    const int lane = threadIdx.x & 63;
    const int n = blockIdx.x * 4 + wv;
    if (n >= Nn) return;

    const int base = offs[n], end = offs[n + 1];
    const float hdn = hd2[n] + b[0];

    float ss = 0.f;
    for (int pos = base + lane; pos < end; pos += 64)
        ss += expf(leakyf(hdn + hs[srcC[pos]]));
    for (int off = 32; off; off >>= 1) ss += __shfl_xor(ss, off);
    float inv = (end > base) ? 1.f / ss : 0.f;

    float a0 = 0.f, a1 = 0.f, a2v = 0.f, a3 = 0.f;
    int pos = base;
    for (; pos + 1 < end; pos += 2) {
        int s0 = srcC[pos], s1 = srcC[pos + 1];
        float pe0 = expf(leakyf(hdn + hs[s0]));
        float pe1 = expf(leakyf(hdn + hs[s1]));
        float aw0 = pe0 * inv + 1.f;
        float aw1 = pe1 * inv + 1.f;
        const unsigned short* v0 = hvpbf + (size_t)s0 * 200;
        const unsigned short* v1 = hvpbf + (size_t)s1 * 200;
        a0  += aw0 * bf2f(v0[lane])       + aw1 * bf2f(v1[lane]);
        a1  += aw0 * bf2f(v0[64 + lane])  + aw1 * bf2f(v1[64 + lane]);
        a2v += aw0 * bf2f(v0[128 + lane]) + aw1 * bf2f(v1[128 + lane]);
        if (lane < 8) a3 += aw0 * bf2f(v0[192 + lane]) + aw1 * bf2f(v1[192 + lane]);
    }
    if (pos < end) {
        int s0 = srcC[pos];
        float pe0 = expf(leakyf(hdn + hs[s0]));
        float aw0 = pe0 * inv + 1.f;
        const unsigned short* v0 = hvpbf + (size_t)s0 * 200;
        a0  += aw0 * bf2f(v0[lane]);
        a1  += aw0 * bf2f(v0[64 + lane]);
        a2v += aw0 * bf2f(v0[128 + lane]);
        if (lane < 8) a3 += aw0 * bf2f(v0[192 + lane]);
    }
    unsigned short* out = APK + (size_t)n * 416;
    out[lane] = f2bf(eluf(a0));
    out[64 + lane] = f2bf(eluf(a1));
    out[128 + lane] = f2bf(eluf(a2v));
    if (lane < 8) out[192 + lane] = f2bf(eluf(a3));
}

// ------------- batchnorm stats: column-owning threads, coalesced -------------
__global__ __launch_bounds__(256) void bnstat2_k(
    const float* __restrict__ h1, float* __restrict__ stats, int Nn)
{
    const int c = threadIdx.x;
    if (c >= 200) return;
    float s = 0.f, s2 = 0.f;
    for (int r = blockIdx.x; r < Nn; r += gridDim.x) {
        float v = h1[(size_t)r * 200 + c];
        s += v; s2 += v * v;
    }
    atomicAdd(&stats[c], s);
    atomicAdd(&stats[G + c], s2);
}

// ------------- out = h0(=d_out) + bn(h1), in place -------------
__global__ __launch_bounds__(256) void final_k(
    float* __restrict__ out, const float* __restrict__ h1,
    const float* __restrict__ stats,
    const float* __restrict__ g, const float* __restrict__ bb, int Nn)
{
    long total = (long)Nn * G;
    for (long idx = (long)blockIdx.x * 256 + threadIdx.x; idx < total;
         idx += (long)gridDim.x * 256) {
        int c = (int)(idx % G);
        float mu  = stats[c] / Nn;
        float var = stats[G + c] / Nn - mu * mu;
        float xh  = (h1[idx] - mu) * rsqrtf(var + 1e-5f);
        out[idx] = out[idx] + g[c] * xh + bb[c];
    }
}

extern "C" void kernel_launch(void* const* d_in, const int* in_sizes, int n_in,
                              void* d_out, int out_size, void* d_ws, size_t ws_size,
                              hipStream_t stream)
{
    const float* node_feats = (const float*)d_in[0];
    const float* edge_feats = (const float*)d_in[1];
    const float* gc_node_W  = (const float*)d_in[2];
    const float* gc_node_b  = (const float*)d_in[3];
    const float* gc_e1_W    = (const float*)d_in[4];
    const float* gc_e1_b    = (const float*)d_in[5];
    const float* gc_e2_W    = (const float*)d_in[6];
    const float* gc_e2_b    = (const float*)d_in[7];
    const float* gc_et_W    = (const float*)d_in[8];
    const float* gc_et_b    = (const float*)d_in[9];
    const float* gc_gru_Wx  = (const float*)d_in[10];
    const float* gc_gru_Wh  = (const float*)d_in[11];
    const float* gc_gru_bx  = (const float*)d_in[12];
    const float* gc_gru_bh  = (const float*)d_in[13];
    const float* l1_e_W     = (const float*)d_in[14];
    const float* l1_e_b     = (const float*)d_in[15];
    const float* l1_pn_W    = (const float*)d_in[16];
    const float* l1_pn_b    = (const float*)d_in[17];
    const float* l1_gru_Wx  = (const float*)d_in[18];
    const float* l1_gru_Wh  = (const float*)d_in[19];
    const float* l1_gru_bx  = (const float*)d_in[20];
    const float* l1_gru_bh  = (const float*)d_in[21];
    const float* l1_bn_g    = (const float*)d_in[22];
    const float* l1_bn_b    = (const float*)d_in[23];
    const int*   src        = (const int*)d_in[24];
    const int*   dst        = (const int*)d_in[25];

    const int Nn = in_sizes[0] / NF;
    const int E  = in_sizes[24];
    const int Mpad = ((Nn + 127) / 128) * 128;

    float* ws = (float*)d_ws;
    size_t o = 0;
    float* hv    = ws + o; o += (size_t)Nn * G;        // hv_new -> h1
    float* cbuf  = ws + o; o += ((size_t)Mpad * 416 + 1) / 2;  // hacc + rzbuf + hvpbf overlay
    _Float16* rzbuf = (_Float16*)cbuf;
    unsigned short* hvpbf = (unsigned short*)cbuf;     // bf16 hvp (dead before rzbuf#2)
    float* sden  = ws + o; o += (size_t)Nn;
    float* hd    = ws + o; o += (size_t)Nn;            // hd (layer1) -> hd2
    float* hs    = ws + o; o += (size_t)Nn;            // layer-2 src-side dot
    float* stats = ws + o; o += 512;
    unsigned short* W1t_g  = (unsigned short*)(ws + o); o += (208 * 192) / 2;
    unsigned short* etWt_g = (unsigned short*)(ws + o); o += (208 * 224) / 2;
    unsigned short* ncWt_g = (unsigned short*)(ws + o); o += (208 * 128) / 2;
    unsigned short* pnWt_g = (unsigned short*)(ws + o); o += (208 * 224) / 2;
    unsigned short* Btrz1  = (unsigned short*)(ws + o); o += (512 * 416) / 2;
    unsigned short* Btn1   = (unsigned short*)(ws + o); o += (512 * 416) / 2;
    unsigned short* Btrz2  = (unsigned short*)(ws + o); o += (512 * 416) / 2;
    unsigned short* Btn2   = (unsigned short*)(ws + o); o += (512 * 416) / 2;
    int* cnt    = (int*)(ws + o); o += (size_t)Nn;
    int* offs   = (int*)(ws + o); o += (size_t)Nn + 1;
    int* cursor = (int*)(ws + o); o += (size_t)Nn;
    int* eidC   = (int*)(ws + o); o += (size_t)E;
    int* srcC   = (int*)(ws + o); o += (size_t)E;
    int* dstC   = (int*)(ws + o); o += (size_t)E;
    unsigned short* apack  = (unsigned short*)(ws + o); o += ((size_t)Mpad * 416 + 1) / 2;
    unsigned short* nodebf = (unsigned short*)(ws + o); o += ((size_t)Nn * NF + 1) / 2;
    // total ~37M floats ~= 148 MB (round-15-proven scale)

    float* h0  = (float*)d_out;
    float* h1  = hv;

    const int gN64 = (Nn + 63) / 64;
    const int gE64 = (E + 63) / 64;
    const int gE256 = (E + 255) / 256;
    const int nWaves = (Nn + 3) / 4;
    const dim3 gGEMM((Mpad / 128), 4);

    // ---------- prep: weights + node bf16 + CSR ----------
    hipMemsetAsync(cnt, 0, (size_t)Nn * sizeof(int), stream);
    tprep_k<<<128, 256, 0, stream>>>(gc_e1_W,   W1t_g,  192, 192, 200, 200);
    tprep_k<<<128, 256, 0, stream>>>(gc_et_W,   etWt_g, 200, 224, 200, 200);
    tprep_k<<<128, 256, 0, stream>>>(gc_node_W, ncWt_g, 128, 128, 200, 200);
    tprep_k<<<128, 256, 0, stream>>>(l1_pn_W,   pnWt_g, 200, 224, 200, 200);
    wgru3_k<<<256, 256, 0, stream>>>(gc_gru_Wx, gc_gru_Wh, Btrz1, Btn1);
    wgru3_k<<<256, 256, 0, stream>>>(l1_gru_Wx, l1_gru_Wh, Btrz2, Btn2);
    bfpack_k<<<2048, 256, 0, stream>>>(node_feats, nodebf, (long)Nn * NF / 8);
    hist_k<<<gE256, 256, 0, stream>>>(dst, cnt, E);
    scan_k<<<1, 256, 0, stream>>>(cnt, offs, cursor, Nn);
    scatter_k<<<gE256, 256, 0, stream>>>(src, dst, cursor, eidC, srcC, dstC, E);

    // ---------- GetContext ----------
    hipMemsetAsync(sden, 0, (size_t)Nn * sizeof(float), stream);
    hipMemsetAsync(cbuf, 0, (size_t)Nn * G * sizeof(float), stream);
    hipMemsetAsync(stats, 0, 512 * sizeof(float), stream);
    hipMemsetAsync(apack, 0, (size_t)Mpad * 416 * sizeof(unsigned short), stream);

    // hv = leaky(node @ ncW + b)  [+ apack-H = bf16(hv)]
    mgemm_k<<<gN64, 256, 0, stream>>>(node_feats, ncWt_g, gc_node_b, hv,
                                      apack, 2, Nn, 128, 4, 136, 1, nullptr);
    hd_k<<<nWaves, 256, 0, stream>>>(hv, gc_e2_W, hd, Nn);

    // hacc[dst] += pexp*he1 (segmented), sden[dst] += pexp
    edgefuse2_k<<<gE64, 256, 0, stream>>>(
        nodebf, edge_feats, srcC, dstC, eidC,
        W1t_g, gc_e1_b, gc_e2_W, gc_e2_b, hd, sden, cbuf, E);

    // apack-X = bf16(elu((hacc/sden) @ etW + etb*[deg>0]))
    mgemm_k<<<gN64, 256, 0, stream>>>(cbuf, etWt_g, gc_et_b, nullptr,
                                      apack, 1, Nn, 200, 7, 232, 0, sden);

    // ---- GRU1: h0 = relu(GRU(elu(c), hv)) ----
    tgemm_k<0><<<gGEMM, 256, 0, stream>>>(apack, Btrz1, gc_gru_bx, gc_gru_bh,
                                          rzbuf, nullptr, nullptr, Nn);
    tgemm_k<1><<<gGEMM, 256, 0, stream>>>(apack, Btn1, gc_gru_bx, gc_gru_bh,
                                          rzbuf, hv, h0, Nn);

    // ---------- GNNLayer ----------
    hdpair_k<<<nWaves, 256, 0, stream>>>(h0, l1_e_W, hd, hs, apack, Nn);

    // hvpbf = bf16(h0 @ pnW + b)
    mgemm_k<<<gN64, 256, 0, stream>>>(h0, pnWt_g, l1_pn_b, nullptr,
                                      hvpbf, 3, Nn, 200, 7, 232, 0, nullptr);

    // apack-X = bf16(elu(c2)), c2 = sum_e (softmax+1) * hvp[src]
    layer2b_k<<<nWaves, 256, 0, stream>>>(hvpbf, hd, hs, l1_e_b,
                                          offs, srcC, apack, Nn);

    // ---- GRU2: h1 = relu(GRU(elu(c2), h0)) ----
    tgemm_k<0><<<gGEMM, 256, 0, stream>>>(apack, Btrz2, l1_gru_bx, l1_gru_bh,
                                          rzbuf, nullptr, nullptr, Nn);
    tgemm_k<1><<<gGEMM, 256, 0, stream>>>(apack, Btn2, l1_gru_bx, l1_gru_bh,
                                          rzbuf, h0, h1, Nn);

    bnstat2_k<<<512, 256, 0, stream>>>(h1, stats, Nn);
    final_k<<<2048, 256, 0, stream>>>((float*)d_out, h1, stats,
                                      l1_bn_g, l1_bn_b, Nn);
}

// Round 17
// 972.933 us; speedup vs baseline: 1.0955x; 1.0955x over previous
//
#include <hip/hip_runtime.h>
#include <math.h>

#define G 200
#define NF 128
#define EF 64

typedef __attribute__((ext_vector_type(8))) short bf16x8;
typedef __attribute__((ext_vector_type(4))) float f32x4;

__device__ __forceinline__ float leakyf(float x) { return x > 0.f ? x : 0.01f * x; }
__device__ __forceinline__ float eluf(float x)   { return x > 0.f ? x : (expf(x) - 1.f); }
__device__ __forceinline__ float sigm(float x)   { return 1.f / (1.f + expf(-x)); }

__device__ __forceinline__ unsigned short f2bf(float x) {
    union { float f; unsigned int u; } v; v.f = x;
    unsigned int r = v.u + 0x7FFF + ((v.u >> 16) & 1);   // RNE
    return (unsigned short)(r >> 16);
}
__device__ __forceinline__ float bf2f(unsigned short u) {
    union { unsigned int i; float f; } v; v.i = ((unsigned int)u) << 16;
    return v.f;
}
__device__ __forceinline__ unsigned int pk2(float a, float b) {
    return (unsigned int)f2bf(a) | ((unsigned int)f2bf(b) << 16);
}

// ---------- generic weight transpose+bf16 prep: Wt[208][kpad] = W[k][n] ----------
__global__ __launch_bounds__(256) void tprep_k(
    const float* __restrict__ W, unsigned short* __restrict__ Wt,
    int Kreal, int kpad, int Nstride, int Nreal)
{
    int total = 208 * kpad;
    for (int i = blockIdx.x * 256 + threadIdx.x; i < total; i += gridDim.x * 256) {
        int n = i / kpad, k = i % kpad;
        Wt[i] = (n < Nreal && k < Kreal) ? f2bf(W[(size_t)k * Nstride + n]) : 0;
    }
}

// ---------- bf16 pack (elementwise, 8/thread): Y = bf16(X) ----------
__global__ __launch_bounds__(256) void bfpack_k(
    const float* __restrict__ X, unsigned short* __restrict__ Y, long n8)
{
    for (long i = (long)blockIdx.x * 256 + threadIdx.x; i < n8;
         i += (long)gridDim.x * 256) {
        const float4* xp = (const float4*)(X + i * 8);
        float4 a = xp[0], b = xp[1];
        uint4 u; u.x = pk2(a.x, a.y); u.y = pk2(a.z, a.w);
        u.z = pk2(b.x, b.y); u.w = pk2(b.z, b.w);
        *(uint4*)&Y[i * 8] = u;
    }
}

// ---------- GRU weight prep for the tiled GEMM ----------
__global__ __launch_bounds__(256) void wgru3_k(
    const float* __restrict__ Wx, const float* __restrict__ Wh,
    unsigned short* __restrict__ Btrz, unsigned short* __restrict__ Btn)
{
    const int total = 512 * 416;
    for (int i = blockIdx.x * 256 + threadIdx.x; i < total; i += gridDim.x * 256) {
        int n = i / 416, k = i % 416;
        float v = 0.f;
        if (n < 416) {
            int gg = (n >= 208) ? 1 : 0;
            int c = n - gg * 208;
            if (c < 200) {
                if (k < 200)                  v = Wx[(size_t)k * 600 + gg * 200 + c];
                else if (k >= 208 && k < 408) v = Wh[(size_t)(k - 208) * 600 + gg * 200 + c];
            }
        }
        Btrz[i] = f2bf(v);

        float u = 0.f;
        int s = n >> 4, cc = n & 15;
        if (s < 26) {
            int c = (s >> 1) * 16 + cc;
            if (c < 200) {
                if (!(s & 1)) { if (k < 200) u = Wx[(size_t)k * 600 + 400 + c]; }
                else { if (k >= 208 && k < 408) u = Wh[(size_t)(k - 208) * 600 + 400 + c]; }
            }
        }
        Btn[i] = f2bf(u);
    }
}

// ---------- tiled 128x128 GEMM, K=416, double-buffered LDS, bf16 MFMA ----------
// EPI 0: RZ[row*416+col] = f16(sigm(acc + bias))
// EPI 1: GRU combine with h read from f32 Hf
template <int EPI>
__global__ __launch_bounds__(256) void tgemm_k(
    const unsigned short* __restrict__ Apk,
    const unsigned short* __restrict__ Bt,
    const float* __restrict__ bx, const float* __restrict__ bh,
    _Float16* __restrict__ RZ,
    const float* __restrict__ Hf,
    float* __restrict__ OUT, int M)
{
    __shared__ __align__(16) unsigned short As[2][128 * 32];
    __shared__ __align__(16) unsigned short Bs[2][128 * 32];

    const int tid = threadIdx.x;
    const int w = tid >> 6, lane = tid & 63, l15 = lane & 15, lq = lane >> 4;
    const int wr = w >> 1, wc = w & 1;
    const int bm = blockIdx.x * 128, bn = blockIdx.y * 128;
    const int r0 = tid >> 2, sl = tid & 3;

    f32x4 acc[4][4];
#pragma unroll
    for (int a = 0; a < 4; ++a)
#pragma unroll
        for (int b = 0; b < 4; ++b) acc[a][b] = (f32x4){0.f, 0.f, 0.f, 0.f};

    {
        uint4 pa0 = *(const uint4*)&Apk[(size_t)(bm + r0) * 416 + sl * 8];
        uint4 pa1 = *(const uint4*)&Apk[(size_t)(bm + 64 + r0) * 416 + sl * 8];
        uint4 pb0 = *(const uint4*)&Bt[(size_t)(bn + r0) * 416 + sl * 8];
        uint4 pb1 = *(const uint4*)&Bt[(size_t)(bn + 64 + r0) * 416 + sl * 8];
        int w0 = sl ^ ((r0 >> 1) & 3), w1 = sl ^ (((r0 + 64) >> 1) & 3);
        *(uint4*)&As[0][r0 * 32 + w0 * 8] = pa0;
        *(uint4*)&As[0][(r0 + 64) * 32 + w1 * 8] = pa1;
        *(uint4*)&Bs[0][r0 * 32 + w0 * 8] = pb0;
        *(uint4*)&Bs[0][(r0 + 64) * 32 + w1 * 8] = pb1;
    }
    __syncthreads();

    int cur = 0;
    for (int c = 0; c < 13; ++c) {
        uint4 pa0, pa1, pb0, pb1;
        if (c < 12) {
            int kc = (c + 1) * 32;
            pa0 = *(const uint4*)&Apk[(size_t)(bm + r0) * 416 + kc + sl * 8];
            pa1 = *(const uint4*)&Apk[(size_t)(bm + 64 + r0) * 416 + kc + sl * 8];
            pb0 = *(const uint4*)&Bt[(size_t)(bn + r0) * 416 + kc + sl * 8];
            pb1 = *(const uint4*)&Bt[(size_t)(bn + 64 + r0) * 416 + kc + sl * 8];
        }
        bf16x8 af[4], bfr[4];
#pragma unroll
        for (int s = 0; s < 4; ++s) {
            int ra = wr * 64 + s * 16 + l15;
            af[s] = *(const bf16x8*)&As[cur][ra * 32 + (lq ^ ((ra >> 1) & 3)) * 8];
            int rb = wc * 64 + s * 16 + l15;
            bfr[s] = *(const bf16x8*)&Bs[cur][rb * 32 + (lq ^ ((rb >> 1) & 3)) * 8];
        }
#pragma unroll
        for (int sr = 0; sr < 4; ++sr)
#pragma unroll
            for (int sc = 0; sc < 4; ++sc)
                acc[sr][sc] = __builtin_amdgcn_mfma_f32_16x16x32_bf16(
                    af[sr], bfr[sc], acc[sr][sc], 0, 0, 0);

        if (c < 12) {
            int nb = cur ^ 1;
            int w0 = sl ^ ((r0 >> 1) & 3), w1 = sl ^ (((r0 + 64) >> 1) & 3);
            *(uint4*)&As[nb][r0 * 32 + w0 * 8] = pa0;
            *(uint4*)&As[nb][(r0 + 64) * 32 + w1 * 8] = pa1;
            *(uint4*)&Bs[nb][r0 * 32 + w0 * 8] = pb0;
            *(uint4*)&Bs[nb][(r0 + 64) * 32 + w1 * 8] = pb1;
        }
        __syncthreads();
        cur ^= 1;
    }

    if (EPI == 0) {
#pragma unroll
        for (int sr = 0; sr < 4; ++sr)
#pragma unroll
            for (int sc = 0; sc < 4; ++sc) {
                int col = bn + wc * 64 + sc * 16 + l15;
                if (col >= 416) continue;
                float bsum = (col < 208) ? (bx[col] + bh[col])
                                         : (bx[col - 8] + bh[col - 8]);
#pragma unroll
                for (int i = 0; i < 4; ++i) {
                    int row = bm + wr * 64 + sr * 16 + lq * 4 + i;
                    if (row < M)
                        RZ[(size_t)row * 416 + col] =
                            (_Float16)sigm(acc[sr][sc][i] + bsum);
                }
            }
    } else {
#pragma unroll
        for (int p = 0; p < 2; ++p) {
            int sglob = (bn >> 4) + wc * 4 + 2 * p;
            int cc = (sglob >> 1) * 16 + l15;
            if (cc >= 200) continue;
            float bxn = bx[400 + cc], bhn = bh[400 + cc];
#pragma unroll
            for (int sr = 0; sr < 4; ++sr)
#pragma unroll
                for (int i = 0; i < 4; ++i) {
                    int row = bm + wr * 64 + sr * 16 + lq * 4 + i;
                    if (row >= M) continue;
                    float rr = (float)RZ[(size_t)row * 416 + cc];
                    float zz = (float)RZ[(size_t)row * 416 + 208 + cc];
                    float hh = Hf[(size_t)row * 200 + cc];
                    float nn = tanhf(acc[sr][2 * p][i] + bxn +
                                     rr * (acc[sr][2 * p + 1][i] + bhn));
                    float o = (1.f - zz) * nn + zz * hh;
                    OUT[(size_t)row * 200 + cc] = fmaxf(o, 0.f);
                }
        }
    }
}

// ---------- CSR build ----------
__global__ __launch_bounds__(256) void hist_k(
    const int* __restrict__ dst, int* __restrict__ cnt, int E)
{
    int i = blockIdx.x * 256 + threadIdx.x;
    if (i < E) atomicAdd(&cnt[dst[i]], 1);
}

__global__ __launch_bounds__(256) void scan_k(
    const int* __restrict__ cnt, int* __restrict__ offs,
    int* __restrict__ cursor, int Nn)
{
    __shared__ int wsum[4];
    const int tid = threadIdx.x;
    const int lane = tid & 63, wv = tid >> 6;
    int carry = 0;
    const int CH = 8;
    for (int base = 0; base < Nn; base += 256 * CH) {
        int v[CH]; int tsum = 0;
        int i0 = base + tid * CH;
#pragma unroll
        for (int j = 0; j < CH; ++j) {
            v[j] = (i0 + j < Nn) ? cnt[i0 + j] : 0;
            tsum += v[j];
        }
        int x = tsum;
        for (int off = 1; off < 64; off <<= 1) {
            int t = __shfl_up(x, off);
            if (lane >= off) x += t;
        }
        if (lane == 63) wsum[wv] = x;
        __syncthreads();
        int wbase = 0;
#pragma unroll
        for (int wq = 0; wq < 4; ++wq) wbase += (wq < wv) ? wsum[wq] : 0;
        int gtot = wsum[0] + wsum[1] + wsum[2] + wsum[3];
        int run = carry + wbase + (x - tsum);
#pragma unroll
        for (int j = 0; j < CH; ++j) {
            int idx = i0 + j;
            if (idx < Nn) { offs[idx] = run; cursor[idx] = run; }
            run += v[j];
        }
        carry += gtot;
        __syncthreads();
    }
    if (tid == 0) offs[Nn] = carry;
}

__global__ __launch_bounds__(256) void scatter_k(
    const int* __restrict__ src, const int* __restrict__ dst,
    int* __restrict__ cursor, int* __restrict__ eidC,
    int* __restrict__ srcC, int* __restrict__ dstC, int E)
{
    int i = blockIdx.x * 256 + threadIdx.x;
    if (i < E) {
        int d = dst[i];
        int pos = atomicAdd(&cursor[d], 1);
        eidC[pos] = i; srcC[pos] = src[i]; dstC[pos] = d;
    }
}

// ---------- dense MFMA GEMM (64-row) with fused A-pack epilogues ----------
// amode 0: OUT f32 = (leaky?)v
// amode 1: APK X-half (stride 416) = bf16(elu(v))
// amode 2: OUT f32 = leaky(v)  AND  APK H-half (stride 416) = bf16(leaky(v))
// amode 3: APK (stride 200) = bf16(v)            (bf16 hvp for layer2b)
__global__ __launch_bounds__(256) void mgemm_k(
    const float* __restrict__ X, const unsigned short* __restrict__ Wt,
    const float* __restrict__ bias, float* __restrict__ OUT,
    unsigned short* __restrict__ APK, int amode,
    int M, int Kreal, int kch, int astr, int leaky,
    const float* __restrict__ xdiv)
{
    __shared__ __align__(16) unsigned short A[64 * 232];
    const int tid = threadIdx.x;
    const int w = tid >> 6, lane = tid & 63, l15 = lane & 15, lq = lane >> 4;
    const int bm = blockIdx.x * 64;
    const int kpad = kch * 32;
    const int nch8 = Kreal >> 3;

    for (int i = tid; i < 64 * nch8; i += 256) {
        int r = i / nch8, ch = i % nch8;
        int grow = bm + r;
        uint4 u = make_uint4(0, 0, 0, 0);
        if (grow < M) {
            const float4* xp = (const float4*)(X + (size_t)grow * Kreal + ch * 8);
            float inv = 1.f;
            if (xdiv) { float dv = xdiv[grow]; inv = (dv > 0.f) ? 1.f / dv : 0.f; }
            float4 a = xp[0], b = xp[1];
            u.x = pk2(a.x * inv, a.y * inv); u.y = pk2(a.z * inv, a.w * inv);
            u.z = pk2(b.x * inv, b.y * inv); u.w = pk2(b.z * inv, b.w * inv);
        }
        *(uint4*)&A[r * astr + ch * 8] = u;
    }
    if (tid < 64) {
        for (int p = Kreal; p < kpad; p += 8)
            *(uint4*)&A[tid * astr + p] = make_uint4(0, 0, 0, 0);
    }
    __syncthreads();

    const int arow = (w * 16 + l15) * astr;
    f32x4 acc[13];
#pragma unroll
    for (int t = 0; t < 13; ++t) acc[t] = (f32x4){0.f, 0.f, 0.f, 0.f};

    for (int c = 0; c < kch; ++c) {
        bf16x8 a = *(const bf16x8*)&A[arow + c * 32 + lq * 8];
#pragma unroll
        for (int t = 0; t < 13; ++t) {
            bf16x8 b = *(const bf16x8*)&Wt[(size_t)(t * 16 + l15) * kpad + c * 32 + lq * 8];
            acc[t] = __builtin_amdgcn_mfma_f32_16x16x32_bf16(a, b, acc[t], 0, 0, 0);
        }
    }

    float rg[4];
#pragma unroll
    for (int i = 0; i < 4; ++i) {
        int grow = bm + w * 16 + lq * 4 + i;
        rg[i] = 1.f;
        if (xdiv && grow < M) rg[i] = (xdiv[grow] > 0.f) ? 1.f : 0.f;
    }

#pragma unroll
    for (int t = 0; t < 13; ++t) {
        int col = t * 16 + l15;
        if (col >= 200) continue;
        float bs = bias[col];
#pragma unroll
        for (int i = 0; i < 4; ++i) {
            int grow = bm + w * 16 + lq * 4 + i;
            if (grow >= M) continue;
            float v = acc[t][i] + bs * rg[i];
            if (amode == 0) {
                OUT[(size_t)grow * 200 + col] = leaky ? leakyf(v) : v;
            } else if (amode == 1) {
                APK[(size_t)grow * 416 + col] = f2bf(eluf(v));
            } else if (amode == 2) {
                float lv = leakyf(v);
                OUT[(size_t)grow * 200 + col] = lv;
                APK[(size_t)grow * 416 + 208 + col] = f2bf(lv);
            } else {
                APK[(size_t)grow * 200 + col] = f2bf(v);
            }
        }
    }
}

// ---------------- hd[n] = x[n,:] . W[0:200] ----------------
__global__ __launch_bounds__(256) void hd_k(
    const float* __restrict__ x, const float* __restrict__ W,
    float* __restrict__ hd, int Nn)
{
    int wid = blockIdx.x * 4 + (threadIdx.x >> 6);
    int lane = threadIdx.x & 63;
    if (wid >= Nn) return;
    float s = 0.f;
    for (int j = lane; j < G; j += 64) s += x[(size_t)wid * G + j] * W[j];
    for (int off = 32; off; off >>= 1) s += __shfl_down(s, off);
    if (lane == 0) hd[wid] = s;
}

// -------- hd2/hs pair + pack h into apack H-half (GRU2's H) --------
__global__ __launch_bounds__(256) void hdpair_k(
    const float* __restrict__ x, const float* __restrict__ W,
    float* __restrict__ hd2, float* __restrict__ hs,
    unsigned short* __restrict__ APK, int Nn)
{
    int wid = blockIdx.x * 4 + (threadIdx.x >> 6);
    int lane = threadIdx.x & 63;
    if (wid >= Nn) return;
    float s1 = 0.f, s2 = 0.f;
    unsigned short* ap = APK + (size_t)wid * 416 + 208;
    for (int j = lane; j < G; j += 64) {
        float v = x[(size_t)wid * G + j];
        s1 = fmaf(v, W[j], s1);
        s2 = fmaf(v, W[200 + j], s2);
        ap[j] = f2bf(v);
    }
    for (int off = 32; off; off >>= 1) {
        s1 += __shfl_down(s1, off);
        s2 += __shfl_down(s2, off);
    }
    if (lane == 0) { hd2[wid] = s1; hs[wid] = s2; }
}

// ============ fused edge kernel (CSR order, MFMA bf16, LDS-staged W) ============
// Node rows gathered from PRE-PACKED bf16 (bit-identical to in-register pk2).
__global__ __launch_bounds__(256) void edgefuse2_k(
    const unsigned short* __restrict__ nodebf, const float* __restrict__ edgef,
    const int* __restrict__ srcC, const int* __restrict__ dstC,
    const int* __restrict__ eidC,
    const unsigned short* __restrict__ W1t, const float* __restrict__ b1,
    const float* __restrict__ e2W, const float* __restrict__ e2b,
    const float* __restrict__ hd,
    float* __restrict__ sden, float* __restrict__ hacc, int E)
{
    __shared__ __align__(16) unsigned short U[64 * 216];
    __shared__ __align__(16) unsigned short Wt[208 * 40];
    __shared__ float rowlg[64];
    __shared__ float pexp_s[64];
    __shared__ int   dst_s[64];

    const int tid  = threadIdx.x;
    const int w    = tid >> 6;
    const int lane = tid & 63;
    const int l15  = lane & 15;
    const int lq   = lane >> 4;
    const int eb   = blockIdx.x * 64;

    {
        const int r4 = tid >> 2, q = tid & 3;
        const int pos = eb + r4;
        if (pos < E) {
            const int se = srcC[pos];
            const int ei = eidC[pos];
            const uint4* np = (const uint4*)(nodebf + (size_t)se * NF);
            const float4* ep = (const float4*)(edgef + (size_t)ei * EF);
            uint4* rowp = (uint4*)(U + r4 * 216);
#pragma unroll
            for (int i = 0; i < 4; ++i)              // node: 128 bf16 = 16 uint4
                rowp[q * 4 + i] = np[q * 4 + i];
            uint4* edp = (uint4*)(U + r4 * 216 + 128);
#pragma unroll
            for (int i = 0; i < 2; ++i) {            // edge: 64 f32 -> 8 uint4
                float4 a = ep[q * 4 + 2 * i];
                float4 b = ep[q * 4 + 2 * i + 1];
                uint4 u; u.x = pk2(a.x, a.y); u.y = pk2(a.z, a.w);
                u.z = pk2(b.x, b.y); u.w = pk2(b.z, b.w);
                edp[q * 2 + i] = u;
            }
        } else {
            uint4 z = make_uint4(0, 0, 0, 0);
            uint4* rowp = (uint4*)(U + r4 * 216);
#pragma unroll
            for (int i = 0; i < 4; ++i) rowp[q * 4 + i] = z;
            uint4* edp = (uint4*)(U + r4 * 216 + 128);
            edp[q * 2] = z; edp[q * 2 + 1] = z;
        }
        if (tid < 64) dst_s[tid] = (eb + tid < E) ? dstC[eb + tid] : -1;
    }
    __syncthreads();

    f32x4 acc[13];
#pragma unroll
    for (int t = 0; t < 13; ++t) acc[t] = (f32x4){0.f, 0.f, 0.f, 0.f};

    for (int c = 0; c < 6; ++c) {
        for (int q = tid; q < 832; q += 256) {
            int n = q >> 2, s = q & 3;
            *(uint4*)(Wt + n * 40 + s * 8) =
                *(const uint4*)(W1t + (size_t)n * 192 + c * 32 + s * 8);
        }
        __syncthreads();
        bf16x8 a = *(const bf16x8*)(U + (w * 16 + l15) * 216 + c * 32 + lq * 8);
#pragma unroll
        for (int t = 0; t < 13; ++t) {
            bf16x8 b = *(const bf16x8*)(Wt + (t * 16 + l15) * 40 + lq * 8);
            acc[t] = __builtin_amdgcn_mfma_f32_16x16x32_bf16(a, b, acc[t], 0, 0, 0);
        }
        __syncthreads();
    }

    float p[4] = {0.f, 0.f, 0.f, 0.f};
#pragma unroll
    for (int t = 0; t < 13; ++t) {
        const int col = t * 16 + l15;
#pragma unroll
        for (int r = 0; r < 4; ++r) {
            const int row = w * 16 + lq * 4 + r;
            float v = 0.f;
            if (col < 200) {
                v = leakyf(acc[t][r] + b1[col]);
                p[r] = fmaf(v, e2W[200 + col], p[r]);
            }
            U[row * 216 + col] = f2bf(v);
        }
    }
#pragma unroll
    for (int r = 0; r < 4; ++r) {
        p[r] += __shfl_xor(p[r], 1);
        p[r] += __shfl_xor(p[r], 2);
        p[r] += __shfl_xor(p[r], 4);
        p[r] += __shfl_xor(p[r], 8);
    }
    if (l15 == 0) {
#pragma unroll
        for (int r = 0; r < 4; ++r) rowlg[w * 16 + lq * 4 + r] = p[r];
    }
    __syncthreads();

    if (tid < 64) {
        float pe = 0.f;
        if (eb + tid < E) {
            float l = leakyf(rowlg[tid] + hd[dst_s[tid]] + e2b[0]);
            pe = expf(l);
            atomicAdd(&sden[dst_s[tid]], pe);
        }
        pexp_s[tid] = pe;
    }
    __syncthreads();

    if (tid < 200) {
        const int c = tid;
        float s = 0.f;
        int cur = dst_s[0];
        for (int r = 0; r < 64; ++r) {
            int d = dst_s[r];
            if (d < 0) break;
            if (d != cur) {
                atomicAdd(&hacc[(size_t)cur * 200 + c], s);
                s = 0.f; cur = d;
            }
            s = fmaf(pexp_s[r], bf2f(U[r * 216 + c]), s);
        }
        atomicAdd(&hacc[(size_t)cur * 200 + c], s);
    }
}

// ============ layer-2: separable logits + softmax; bf16 hvp gather ============
__global__ __launch_bounds__(256) void layer2b_k(
    const unsigned short* __restrict__ hvpbf,
    const float* __restrict__ hd2, const float* __restrict__ hs,
    const float* __restrict__ b,
    const int* __restrict__ offs, const int* __restrict__ srcC,
    unsigned short* __restrict__ APK, int Nn)
{
    const int wv = threadIdx.x >> 6;
    const int lane = threadIdx.x & 63;
    const int n = blockIdx.x * 4 + wv;
    if (n >= Nn) return;

    const int base = offs[n], end = offs[n + 1];
    const float hdn = hd2[n] + b[0];

    float ss = 0.f;
    for (int pos = base + lane; pos < end; pos += 64)
        ss += expf(leakyf(hdn + hs[srcC[pos]]));
    for (int off = 32; off; off >>= 1) ss += __shfl_xor(ss, off);
    float inv = (end > base) ? 1.f / ss : 0.f;

    float a0 = 0.f, a1 = 0.f, a2v = 0.f, a3 = 0.f;
    for (int pos = base; pos < end; ++pos) {
        int sidx = srcC[pos];
        float pe = expf(leakyf(hdn + hs[sidx]));
        float aw = pe * inv + 1.f;
        const unsigned short* vr = hvpbf + (size_t)sidx * 200;
        a0  += aw * bf2f(vr[lane]);
        a1  += aw * bf2f(vr[64 + lane]);
        a2v += aw * bf2f(vr[128 + lane]);
        if (lane < 8) a3 += aw * bf2f(vr[192 + lane]);
    }
    unsigned short* out = APK + (size_t)n * 416;
    out[lane] = f2bf(eluf(a0));
    out[64 + lane] = f2bf(eluf(a1));
    out[128 + lane] = f2bf(eluf(a2v));
    if (lane < 8) out[192 + lane] = f2bf(eluf(a3));
}

// ------------- batchnorm stats: column-owning threads, coalesced -------------
__global__ __launch_bounds__(256) void bnstat2_k(
    const float* __restrict__ h1, float* __restrict__ stats, int Nn)
{
    const int c = threadIdx.x;
    if (c >= 200) return;
    float s = 0.f, s2 = 0.f;
    for (int r = blockIdx.x; r < Nn; r += gridDim.x) {
        float v = h1[(size_t)r * 200 + c];
        s += v; s2 += v * v;
    }
    atomicAdd(&stats[c], s);
    atomicAdd(&stats[G + c], s2);
}

// ------------- out = h0(=d_out) + bn(h1), in place -------------
__global__ __launch_bounds__(256) void final_k(
    float* __restrict__ out, const float* __restrict__ h1,
    const float* __restrict__ stats,
    const float* __restrict__ g, const float* __restrict__ bb, int Nn)
{
    long total = (long)Nn * G;
    for (long idx = (long)blockIdx.x * 256 + threadIdx.x; idx < total;
         idx += (long)gridDim.x * 256) {
        int c = (int)(idx % G);
        float mu  = stats[c] / Nn;
        float var = stats[G + c] / Nn - mu * mu;
        float xh  = (h1[idx] - mu) * rsqrtf(var + 1e-5f);
        out[idx] = out[idx] + g[c] * xh + bb[c];
    }
}

extern "C" void kernel_launch(void* const* d_in, const int* in_sizes, int n_in,
                              void* d_out, int out_size, void* d_ws, size_t ws_size,
                              hipStream_t stream)
{
    const float* node_feats = (const float*)d_in[0];
    const float* edge_feats = (const float*)d_in[1];
    const float* gc_node_W  = (const float*)d_in[2];
    const float* gc_node_b  = (const float*)d_in[3];
    const float* gc_e1_W    = (const float*)d_in[4];
    const float* gc_e1_b    = (const float*)d_in[5];
    const float* gc_e2_W    = (const float*)d_in[6];
    const float* gc_e2_b    = (const float*)d_in[7];
    const float* gc_et_W    = (const float*)d_in[8];
    const float* gc_et_b    = (const float*)d_in[9];
    const float* gc_gru_Wx  = (const float*)d_in[10];
    const float* gc_gru_Wh  = (const float*)d_in[11];
    const float* gc_gru_bx  = (const float*)d_in[12];
    const float* gc_gru_bh  = (const float*)d_in[13];
    const float* l1_e_W     = (const float*)d_in[14];
    const float* l1_e_b     = (const float*)d_in[15];
    const float* l1_pn_W    = (const float*)d_in[16];
    const float* l1_pn_b    = (const float*)d_in[17];
    const float* l1_gru_Wx  = (const float*)d_in[18];
    const float* l1_gru_Wh  = (const float*)d_in[19];
    const float* l1_gru_bx  = (const float*)d_in[20];
    const float* l1_gru_bh  = (const float*)d_in[21];
    const float* l1_bn_g    = (const float*)d_in[22];
    const float* l1_bn_b    = (const float*)d_in[23];
    const int*   src        = (const int*)d_in[24];
    const int*   dst        = (const int*)d_in[25];

    const int Nn = in_sizes[0] / NF;
    const int E  = in_sizes[24];
    const int Mpad = ((Nn + 127) / 128) * 128;

    float* ws = (float*)d_ws;
    size_t o = 0;
    float* hv    = ws + o; o += (size_t)Nn * G;        // hv_new -> h1
    float* cbuf  = ws + o; o += ((size_t)Mpad * 416 + 1) / 2;  // hacc + rzbuf + hvpbf overlay
    _Float16* rzbuf = (_Float16*)cbuf;
    unsigned short* hvpbf = (unsigned short*)cbuf;     // bf16 hvp (dead before rzbuf#2)
    float* sden  = ws + o; o += (size_t)Nn;
    float* hd    = ws + o; o += (size_t)Nn;            // hd (layer1) -> hd2
    float* hs    = ws + o; o += (size_t)Nn;            // layer-2 src-side dot
    float* stats = ws + o; o += 512;
    unsigned short* W1t_g  = (unsigned short*)(ws + o); o += (208 * 192) / 2;
    unsigned short* etWt_g = (unsigned short*)(ws + o); o += (208 * 224) / 2;
    unsigned short* ncWt_g = (unsigned short*)(ws + o); o += (208 * 128) / 2;
    unsigned short* pnWt_g = (unsigned short*)(ws + o); o += (208 * 224) / 2;
    unsigned short* Btrz1  = (unsigned short*)(ws + o); o += (512 * 416) / 2;
    unsigned short* Btn1   = (unsigned short*)(ws + o); o += (512 * 416) / 2;
    unsigned short* Btrz2  = (unsigned short*)(ws + o); o += (512 * 416) / 2;
    unsigned short* Btn2   = (unsigned short*)(ws + o); o += (512 * 416) / 2;
    int* cnt    = (int*)(ws + o); o += (size_t)Nn;
    int* offs   = (int*)(ws + o); o += (size_t)Nn + 1;
    int* cursor = (int*)(ws + o); o += (size_t)Nn;
    int* eidC   = (int*)(ws + o); o += (size_t)E;
    int* srcC   = (int*)(ws + o); o += (size_t)E;
    int* dstC   = (int*)(ws + o); o += (size_t)E;
    unsigned short* apack  = (unsigned short*)(ws + o); o += ((size_t)Mpad * 416 + 1) / 2;
    unsigned short* nodebf = (unsigned short*)(ws + o); o += ((size_t)Nn * NF + 1) / 2;
    // total ~37M floats ~= 148 MB (round-15-proven scale)

    float* h0  = (float*)d_out;
    float* h1  = hv;

    const int gN64 = (Nn + 63) / 64;
    const int gE64 = (E + 63) / 64;
    const int gE256 = (E + 255) / 256;
    const int nWaves = (Nn + 3) / 4;
    const dim3 gGEMM((Mpad / 128), 4);

    // ---------- prep: weights + node bf16 + CSR ----------
    hipMemsetAsync(cnt, 0, (size_t)Nn * sizeof(int), stream);
    tprep_k<<<128, 256, 0, stream>>>(gc_e1_W,   W1t_g,  192, 192, 200, 200);
    tprep_k<<<128, 256, 0, stream>>>(gc_et_W,   etWt_g, 200, 224, 200, 200);
    tprep_k<<<128, 256, 0, stream>>>(gc_node_W, ncWt_g, 128, 128, 200, 200);
    tprep_k<<<128, 256, 0, stream>>>(l1_pn_W,   pnWt_g, 200, 224, 200, 200);
    wgru3_k<<<256, 256, 0, stream>>>(gc_gru_Wx, gc_gru_Wh, Btrz1, Btn1);
    wgru3_k<<<256, 256, 0, stream>>>(l1_gru_Wx, l1_gru_Wh, Btrz2, Btn2);
    bfpack_k<<<2048, 256, 0, stream>>>(node_feats, nodebf, (long)Nn * NF / 8);
    hist_k<<<gE256, 256, 0, stream>>>(dst, cnt, E);
    scan_k<<<1, 256, 0, stream>>>(cnt, offs, cursor, Nn);
    scatter_k<<<gE256, 256, 0, stream>>>(src, dst, cursor, eidC, srcC, dstC, E);

    // ---------- GetContext ----------
    hipMemsetAsync(sden, 0, (size_t)Nn * sizeof(float), stream);
    hipMemsetAsync(cbuf, 0, (size_t)Nn * G * sizeof(float), stream);
    hipMemsetAsync(stats, 0, 512 * sizeof(float), stream);
    hipMemsetAsync(apack, 0, (size_t)Mpad * 416 * sizeof(unsigned short), stream);

    // hv = leaky(node @ ncW + b)  [+ apack-H = bf16(hv)]
    mgemm_k<<<gN64, 256, 0, stream>>>(node_feats, ncWt_g, gc_node_b, hv,
                                      apack, 2, Nn, 128, 4, 136, 1, nullptr);
    hd_k<<<nWaves, 256, 0, stream>>>(hv, gc_e2_W, hd, Nn);

    // hacc[dst] += pexp*he1 (segmented), sden[dst] += pexp  (bf16 node gather)
    edgefuse2_k<<<gE64, 256, 0, stream>>>(
        nodebf, edge_feats, srcC, dstC, eidC,
        W1t_g, gc_e1_b, gc_e2_W, gc_e2_b, hd, sden, cbuf, E);

    // apack-X = bf16(elu((hacc/sden) @ etW + etb*[deg>0]))
    mgemm_k<<<gN64, 256, 0, stream>>>(cbuf, etWt_g, gc_et_b, nullptr,
                                      apack, 1, Nn, 200, 7, 232, 0, sden);

    // ---- GRU1: h0 = relu(GRU(elu(c), hv)) ----
    tgemm_k<0><<<gGEMM, 256, 0, stream>>>(apack, Btrz1, gc_gru_bx, gc_gru_bh,
                                          rzbuf, nullptr, nullptr, Nn);
    tgemm_k<1><<<gGEMM, 256, 0, stream>>>(apack, Btn1, gc_gru_bx, gc_gru_bh,
                                          rzbuf, hv, h0, Nn);

    // ---------- GNNLayer ----------
    hdpair_k<<<nWaves, 256, 0, stream>>>(h0, l1_e_W, hd, hs, apack, Nn);

    // hvpbf = bf16(h0 @ pnW + b)
    mgemm_k<<<gN64, 256, 0, stream>>>(h0, pnWt_g, l1_pn_b, nullptr,
                                      hvpbf, 3, Nn, 200, 7, 232, 0, nullptr);

    // apack-X = bf16(elu(c2)), c2 = sum_e (softmax+1) * hvp[src]  (bf16 gather)
    layer2b_k<<<nWaves, 256, 0, stream>>>(hvpbf, hd, hs, l1_e_b,
                                          offs, srcC, apack, Nn);

    // ---- GRU2: h1 = relu(GRU(elu(c2), h0)) ----
    tgemm_k<0><<<gGEMM, 256, 0, stream>>>(apack, Btrz2, l1_gru_bx, l1_gru_bh,
                                          rzbuf, nullptr, nullptr, Nn);
    tgemm_k<1><<<gGEMM, 256, 0, stream>>>(apack, Btn2, l1_gru_bx, l1_gru_bh,
                                          rzbuf, h0, h1, Nn);

    bnstat2_k<<<512, 256, 0, stream>>>(h1, stats, Nn);
    final_k<<<2048, 256, 0, stream>>>((float*)d_out, h1, stats,
                                      l1_bn_g, l1_bn_b, Nn);
}